// Round 9
// baseline (1170.270 us; speedup 1.0000x reference)
//
#include <hip/hip_runtime.h>
#include <stdint.h>

// LSTM_Trend: B=256, T=512, F=64, H=512, P=24.
// Persistent kernel: 256 WGs x 256 threads (1/CU) = 16 batch-groups x 16
// hidden-groups. Weights register-resident as MFMA B-fragments.
//
// R9 = R8 (1033us) + two critical-path cuts. Transport untouched (XCD-local
// sc0 stores verified by rendezvous; sc0sc1 loads hit dirty local-L2 lines).
// Counter-derived model: effective clock ~720MHz (MfmaUtil arithmetic vs
// wall, consistent across R0/R7/R8); step = ~1520 core-cy of which ~465
// busy. The stall is barriers + the serialized poll tail + MFMA dep chains
// (1 wave/SIMD, nothing covers bubbles). SQ_LDS_BANK_CONFLICT 3.775e7 is
// b128-inherent (identical across disjoint layouts R0/R8) -- not actionable.
//  1. FOUR MFMA accumulator chains (R6/R7-proven): dep depth 18 -> 9,
//     MFMA block ~360 -> ~200 cy.
//  2. FUSED PER-THREAD POLL+LOAD, S3 deleted (2 barriers/step): thread
//     (wv,ln) owns producer chunk kk = wv*4 + (ln>>4), row = ln&15. It
//     polls ONE flag dword (producer kk's act-wave row>>2), then loads its
//     64B span (4 x ld128, dwords kk*16.. of its row) and writes granules
//     kk*4+i row-frags to LDS (8-lane phase slots (4kk+i+row)&7: distinct
//     -> conflict-free). Each thread progresses independently; the S1
//     barrier provides the only WG-wide join. rule #18 fence after the
//     poll waitcnt (compare is register-only).
// Overwrite safety (2 barriers): producer's act(u+2) overwrites parity of
// h(u+1); it reached there only after observing all flags >= u+2 at its
// iter-(u+1) poll; a flag u+2 is published after that WG passed S1(u+1),
// which is after its iter-u h(u+1) loads completed. FC head reads h_T
// from LDS (tail load made unconditional at t=511).

namespace {
constexpr int T_STEPS = 512;
constexpr int FEA  = 64;
constexpr int HID  = 512;
constexpr int NKI  = 18;          // 16 h k-iters + 2 x k-iters
constexpr int GSTR = 132;         // gates LDS row stride (floats)
constexpr int RPG  = 16;          // batch rows per group
constexpr int GPITCH = 136;       // uint16 elems per granule (272 B pitch)
constexpr size_t HBUF_DW  = 256ull * 256;       // packed h dwords per parity
constexpr size_t FLAG_OFF = 2 * HBUF_DW;        // 16 groups x 64 wave-flags
constexpr size_t GRZ_OFF  = FLAG_OFF + 16 * 64; // gmask[16], gcnt[16]

typedef __bf16   bf16x8 __attribute__((ext_vector_type(8)));
typedef uint16_t u16x8  __attribute__((ext_vector_type(8)));
typedef float    f32x4  __attribute__((ext_vector_type(4)));
typedef uint32_t u32x4  __attribute__((ext_vector_type(4)));

union V8 { u16x8 u; bf16x8 b; u32x4 q; };

__device__ __forceinline__ float bf2f(uint16_t u) {
  union { uint32_t i; float f; } v; v.i = (uint32_t)u << 16; return v.f;
}
__device__ __forceinline__ uint16_t f2bf(float f) {
  union { float f; uint32_t i; } v; v.f = f;
  uint32_t x = v.i;
  return (uint16_t)((x + 0x7FFFu + ((x >> 16) & 1u)) >> 16);  // RNE
}
__device__ __forceinline__ float sigmoid_f(float x) {
  return 1.0f / (1.0f + __expf(-x));
}
__device__ __forceinline__ float tanh_f(float x) {
  float e = __expf(-2.0f * fabsf(x));
  float t = (1.0f - e) / (1.0f + e);
  return copysignf(t, x);
}
__device__ __forceinline__ bf16x8 load8(const void* base, size_t elem_off,
                                        bool fp32m) {
  V8 r;
  if (fp32m) {
    const float* p = (const float*)base + elem_off;
#pragma unroll
    for (int i = 0; i < 8; ++i) r.u[i] = f2bf(p[i]);
  } else {
    r.q = *(const u32x4*)((const uint16_t*)base + elem_off);
  }
  return r.b;
}
__device__ __forceinline__ float loadf(const void* base, int idx, bool fp32m) {
  return fp32m ? ((const float*)base)[idx] : bf2f(((const uint16_t*)base)[idx]);
}
__device__ __forceinline__ uint2 ldx4(const void* x, size_t elem_off,
                                      bool fp32m) {  // 4 x-vals -> 4 bf16
  if (fp32m) {
    float4 v = *(const float4*)((const float*)x + elem_off);
    uint2 w;
    w.x = (uint32_t)f2bf(v.x) | ((uint32_t)f2bf(v.y) << 16);
    w.y = (uint32_t)f2bf(v.z) | ((uint32_t)f2bf(v.w) << 16);
    return w;
  }
  return *(const uint2*)((const uint16_t*)x + elem_off);
}

// ---- exchange memory ops --------------------------------------------------
__device__ __forceinline__ uint32_t ld32_sc01(const uint32_t* p) {
  uint32_t v;
  asm volatile("global_load_dword %0, %1, off sc0 sc1"
               : "=v"(v) : "v"(p) : "memory");
  return v;
}
__device__ __forceinline__ u32x4 ld128_sc01(const uint32_t* p) {
  u32x4 v;
  asm volatile("global_load_dwordx4 %0, %1, off sc0 sc1"
               : "=v"(v) : "v"(p) : "memory");
  return v;
}
__device__ __forceinline__ void st32_x(uint32_t* p, uint32_t v, bool xl) {
  if (xl) asm volatile("global_store_dword %0, %1, off sc0"
                       :: "v"(p), "v"(v) : "memory");
  else    asm volatile("global_store_dword %0, %1, off sc0 sc1"
                       :: "v"(p), "v"(v) : "memory");
}
__device__ __forceinline__ void waitcnt_vm0() {
  asm volatile("s_waitcnt vmcnt(0)" ::: "memory");
}
// rule #18: register-only consumers (compares/MFMA) get hoisted past an
// inline-asm waitcnt; sched_barrier(0) pins them.
__device__ __forceinline__ void waitcnt_vm0_fence() {
  asm volatile("s_waitcnt vmcnt(0)" ::: "memory");
  __builtin_amdgcn_sched_barrier(0);
}
} // namespace

__global__ __launch_bounds__(256, 1) void lstm_persistent(
    const void* __restrict__ x,      // [256][512][64]
    const void* __restrict__ W_ih,   // [2048][64]
    const void* __restrict__ W_hh,   // [2048][512]
    const void* __restrict__ b_ih,   // [2048]
    const void* __restrict__ b_hh,   // [2048]
    const void* __restrict__ W_fc,   // [1536][512]
    const void* __restrict__ b_fc,   // [1536]
    void* __restrict__ out,          // [256][1536]
    uint32_t* __restrict__ dbuf)     // ws: [2][256][256] h + flags + rdzv
{
  __shared__ __align__(16) uint16_t Als[72 * GPITCH];  // frag-major A tile
  __shared__ float Gls[RPG * GSTR];     // gate pre-activations
  __shared__ int   sflag, sok;

  const int tid = threadIdx.x;
  const int wv  = tid >> 6;              // wave 0..3
  const int ln  = tid & 63;
  const int nl  = ln & 15;               // MFMA m/n lane index (row)
  const int kq  = ln >> 4;               // MFMA k-quad
  const int bg  = blockIdx.x & 15;       // batch group
  const int wgi = blockIdx.x >> 4;       // hidden group 0..15
  const int r0  = bg * RPG;              // first batch row of this group

  // ---- per-group XCD-identity rendezvous (one-time, R4-proven) ------------
  if (tid == 0) {
    uint32_t xcc;
    asm volatile("s_getreg_b32 %0, hwreg(HW_REG_XCC_ID)" : "=s"(xcc));
    unsigned* gmask = (unsigned*)(dbuf + GRZ_OFF) + bg;
    unsigned* gcnt  = (unsigned*)(dbuf + GRZ_OFF) + 16 + bg;
    atomicOr(gmask, 1u << (xcc & 31));
    __threadfence();
    atomicAdd(gcnt, 1u);
    while (atomicAdd(gcnt, 0u) < 16u) __builtin_amdgcn_s_sleep(1);
    __threadfence();
    unsigned m = atomicOr(gmask, 0u);
    sok = (__popc(m) == 1) ? 1 : 0;
  }

  // ---- dtype sniff (block-uniform): fp32 read as bf16 -> huge exponents
  if (tid == 1) sflag = 0;
  __syncthreads();
  {
    float a = fabsf(bf2f(((const uint16_t*)b_ih)[tid]));
    if (a > 1.0f) atomicOr(&sflag, 1);
  }
  __syncthreads();
  const bool fp32m = (sflag != 0);
  const bool xloc  = (sok != 0);

  // wave owns cols [wv*32, wv*32+32) as two 16-col subtiles sharing one A-frag
  bf16x8 breg[2][NKI];
  float  bias[2];
#pragma unroll
  for (int s = 0; s < 2; ++s) {
    int col  = wv * 32 + s * 16 + nl;    // 0..127
    int gate = col & 3;
    int unit = col >> 2;                 // 0..31
    int gcol = gate * HID + wgi * 32 + unit;
#pragma unroll
    for (int kk = 0; kk < NKI; ++kk) {
      int k0 = kk * 32 + kq * 8;
      if (k0 < HID)
        breg[s][kk] = load8(W_hh, (size_t)gcol * HID + k0, fp32m);
      else
        breg[s][kk] = load8(W_ih, (size_t)gcol * FEA + (k0 - HID), fp32m);
    }
    bias[s] = loadf(b_ih, gcol, fp32m) + loadf(b_hh, gcol, fp32m);
  }

  // act roles: row ar (0..15), units au, au+1; wave wv covers ar = 4wv..4wv+3
  const int ar  = tid >> 4;
  const int au  = (tid & 15) * 2;
  const int hdw = (r0 + ar) * 256 + wgi * 16 + (tid & 15);  // packed h dword
  float c0 = 0.0f, c1 = 0.0f;

  // x staging roles: row = tid>>4, class sc = tid&15
  const int srow = tid >> 4;
  const int sc   = tid & 15;

  // fused poll+load roles: thread (wv,ln) owns producer chunk pkk, row prow
  const int prow = ln & 15;
  const int pkk  = wv * 4 + (ln >> 4);   // 0..15 = producer WG / h k-chunk

  uint32_t* flagw = dbuf + FLAG_OFF + bg * 64 + wgi * 4 + wv;   // producer
  const uint32_t* fb0 = dbuf + FLAG_OFF + bg * 64;
  const uint32_t* pflag = fb0 + pkk * 4 + (prow >> 2);          // consumer

  // ---- prologue: h(0)=0 in LDS (granules 0..63), stage x(0) ----
  {
    u32x4 z = {0, 0, 0, 0};
    for (int i = tid; i < 64 * GPITCH / 8; i += 256)
      *(u32x4*)&Als[i * 8] = z;
  }
  {
    int gx = sc & 7, hf = sc >> 3;
    size_t off = (size_t)(r0 + srow) * (T_STEPS * FEA) + gx * 8 + hf * 4;
    uint2 w = ldx4(x, off, fp32m);
    *(uint2*)&Als[(64 + gx) * GPITCH + srow * 8 + hf * 4] = w;
  }

  for (int t = 0; t < T_STEPS; ++t) {
    __syncthreads();                     // S1: A tile staged

    // ---- gates = A @ W^T + bias: 18 k-iters, 4 accumulator chains ----
    f32x4 c0a, c0b, c1a, c1b;
#pragma unroll
    for (int i = 0; i < 4; ++i) {
      c0a[i] = bias[0]; c1a[i] = bias[1]; c0b[i] = 0.0f; c1b[i] = 0.0f;
    }
#pragma unroll
    for (int kk = 0; kk < NKI; ++kk) {
      bf16x8 a = *(const bf16x8*)&Als[(4 * kk + kq) * GPITCH + nl * 8];
      if (kk & 1) {
        c0b = __builtin_amdgcn_mfma_f32_16x16x32_bf16(a, breg[0][kk], c0b, 0, 0, 0);
        c1b = __builtin_amdgcn_mfma_f32_16x16x32_bf16(a, breg[1][kk], c1b, 0, 0, 0);
      } else {
        c0a = __builtin_amdgcn_mfma_f32_16x16x32_bf16(a, breg[0][kk], c0a, 0, 0, 0);
        c1a = __builtin_amdgcn_mfma_f32_16x16x32_bf16(a, breg[1][kk], c1a, 0, 0, 0);
      }
    }
    f32x4 A0 = c0a + c0b, A1 = c1a + c1b;
#pragma unroll
    for (int r = 0; r < 4; ++r) {
      Gls[(kq * 4 + r) * GSTR + wv * 32 + nl]      = A0[r];
      Gls[(kq * 4 + r) * GSTR + wv * 32 + 16 + nl] = A1[r];
    }
    __syncthreads();                     // S2: gates ready, A tile free

    const uint32_t tg = (uint32_t)(t + 1);
    const bool havex = (t + 1 < T_STEPS);

    // ---- act: cell update; h store; WAVE drain; per-wave flag ----
    {
      const f32x4* gp = (const f32x4*)&Gls[ar * GSTR + au * 4];
      f32x4 ga = gp[0], gb = gp[1];
      c0 = sigmoid_f(ga[1]) * c0 + sigmoid_f(ga[0]) * tanh_f(ga[2]);
      float h0 = sigmoid_f(ga[3]) * tanh_f(c0);
      c1 = sigmoid_f(gb[1]) * c1 + sigmoid_f(gb[0]) * tanh_f(gb[2]);
      float h1 = sigmoid_f(gb[3]) * tanh_f(c1);
      uint32_t hp = (uint32_t)f2bf(h0) | ((uint32_t)f2bf(h1) << 16);
      st32_x(dbuf + (size_t)(tg & 1) * HBUF_DW + hdw, hp, xloc);
      waitcnt_vm0();                     // this wave's h stores at L2
      if (ln == 0) st32_x(flagw, tg, xloc);
    }

    // ---- stage x(t+1) (x region free after S2; overlaps flag latency) ----
    if (havex) {
      int gx = sc & 7, hf = sc >> 3;
      size_t off = (size_t)(r0 + srow) * (T_STEPS * FEA)
                 + (size_t)(t + 1) * FEA + gx * 8 + hf * 4;
      uint2 w = ldx4(x, off, fp32m);
      *(uint2*)&Als[(64 + gx) * GPITCH + srow * 8 + hf * 4] = w;
    }

    // ---- fused per-thread poll + load + LDS write (no barrier here) ----
    {
      for (;;) {
        uint32_t f = ld32_sc01(pflag);
        waitcnt_vm0_fence();             // fence: compare is register-only
        if (f >= tg) break;
      }
      const uint32_t* src = dbuf + (size_t)(tg & 1) * HBUF_DW
                          + (size_t)(r0 + prow) * 256 + pkk * 16;
      u32x4 v0 = ld128_sc01(src + 0);
      u32x4 v1 = ld128_sc01(src + 4);
      u32x4 v2 = ld128_sc01(src + 8);
      u32x4 v3 = ld128_sc01(src + 12);
      waitcnt_vm0();                     // LDS writes below (memory-ordered)
      uint16_t* d = &Als[(pkk * 4) * GPITCH + prow * 8];
      *(u32x4*)(d + 0 * GPITCH) = v0;
      *(u32x4*)(d + 1 * GPITCH) = v1;
      *(u32x4*)(d + 2 * GPITCH) = v2;
      *(u32x4*)(d + 3 * GPITCH) = v3;
    }
  }
  __syncthreads();                       // h_T (t=511 tail) resident in LDS

  // ---- FC head: out = h_T @ W_fc^T + b_fc (A-frags straight from LDS) ----
  int gwave = wgi * 4 + wv;              // 0..63 within the batch group
  for (int tile = gwave; tile < 96; tile += 64) {
    int n = tile * 16 + nl;              // out column
    float bs = loadf(b_fc, n, fp32m);
    f32x4 acc; acc[0] = bs; acc[1] = bs; acc[2] = bs; acc[3] = bs;
#pragma unroll
    for (int kk = 0; kk < 16; ++kk) {
      bf16x8 a = *(const bf16x8*)&Als[(4 * kk + kq) * GPITCH + nl * 8];
      bf16x8 b = load8(W_fc, (size_t)n * HID + kk * 32 + kq * 8, fp32m);
      acc = __builtin_amdgcn_mfma_f32_16x16x32_bf16(a, b, acc, 0, 0, 0);
    }
#pragma unroll
    for (int r = 0; r < 4; ++r) {
      int row = r0 + kq * 4 + r;
      if (fp32m) ((float*)out)[(size_t)row * 1536 + n] = acc[r];
      else       ((uint16_t*)out)[(size_t)row * 1536 + n] = f2bf(acc[r]);
    }
  }
}

extern "C" void kernel_launch(void* const* d_in, const int* in_sizes, int n_in,
                              void* d_out, int out_size, void* d_ws, size_t ws_size,
                              hipStream_t stream) {
  const void* x    = d_in[0];
  const void* W_ih = d_in[1];
  const void* W_hh = d_in[2];
  const void* b_ih = d_in[3];
  const void* b_hh = d_in[4];
  const void* W_fc = d_in[5];
  const void* b_fc = d_in[6];
  uint32_t* dbuf = (uint32_t*)d_ws;

  // flags (16x64 dwords) + rendezvous (gmask[16], gcnt[16]) start at 0 each
  // call (ws is poisoned 0xAA; poisoned gmask -> safe sc0sc1 fallback).
  hipMemsetAsync((void*)(dbuf + FLAG_OFF), 0,
                 (16 * 64 + 32) * sizeof(uint32_t), stream);

  lstm_persistent<<<dim3(256), dim3(256), 0, stream>>>(
      x, W_ih, W_hh, b_ih, b_hh, W_fc, b_fc, d_out, dbuf);
}